// Round 1
// baseline (390.606 us; speedup 1.0000x reference)
//
#include <hip/hip_runtime.h>
#include <hip/hip_bf16.h>

typedef __attribute__((ext_vector_type(4))) float float4v;
typedef __attribute__((ext_vector_type(8))) __bf16 bf16x8;
typedef __attribute__((ext_vector_type(4))) unsigned short ushort4v;
typedef __attribute__((ext_vector_type(8))) unsigned short ushort8v;

constexpr int NTOK = 50176;
constexpr int DIM  = 384;
constexpr int HID  = 1536;
constexpr int BM   = 128;
constexpr int BH   = 64;
constexpr int NTHREADS = 512;
constexpr int NBLOCKS  = NTOK / BM;   // 392
constexpr int NCHUNK   = HID / BH;    // 24

// workspace element offsets (ushort = bf16 bits)
constexpr int WS_W1P  = 0;                       // [1536][384]  W1^T, k(=dim) contiguous
constexpr int WS_W2P  = HID * DIM;               // [384][1536]  W2^T, k(=hid) contiguous
constexpr int WS_WDT  = 2 * HID * DIM;           // [32][384]    w_down^T (rows 24..31 zero)
constexpr int WS_WUPT = 2 * HID * DIM + 32*DIM;  // [384][32]    w_up^T   (cols 24..31 zero)
constexpr int WS_ELEMS = 2*HID*DIM + 32*DIM + DIM*32;  // 1204224
constexpr size_t WS_BYTES_NEEDED = (size_t)WS_ELEMS * 2;

// LDS byte offsets (total exactly 160 KiB)
constexpr int L_XS = 0;        // [128][384] bf16, row stride 768B, swizzled
constexpr int L_WS = 98304;    // 48KB shared: W1T-mode [64][384] (768B) or W2T-mode [384][64] (128B)
constexpr int L_HS = 147456;   // [128][64] bf16, row stride 128B, swizzled
constexpr int LDS_BYTES = 163840;

__device__ __forceinline__ unsigned short f2bf(float f) {
  __hip_bfloat16 h = __float2bfloat16(f);
  return *reinterpret_cast<unsigned short*>(&h);
}

__device__ __forceinline__ float gelu_f(float v) {
  // tanh-form GELU; max abs dev from exact-erf gelu ~3e-4, far under 2.1e-2 budget
  float u = 0.7978845608f * (v + 0.044715f * v * v * v);
  float e = __expf(2.0f * u);
  float t = 1.0f - 2.0f / (e + 1.0f);
  return 0.5f * v * (1.0f + t);
}

// ---------------- pack kernel: f32 weights -> pre-transposed bf16 in ws ----------------
__global__ __launch_bounds__(256) void pack_weights_k(
    const float* __restrict__ W1, const float* __restrict__ W2,
    const float* __restrict__ wd, const float* __restrict__ wu,
    unsigned short* __restrict__ wsp)
{
  int i = blockIdx.x * 256 + threadIdx.x;
  if (i < HID * DIM) {                       // W1p[f][d] = W1[d][f]
    int f = i / DIM, d = i % DIM;
    wsp[WS_W1P + i] = f2bf(W1[d * HID + f]);
  } else if (i < 2 * HID * DIM) {            // W2p[d][h] = W2[h][d]
    int j = i - HID * DIM;
    int d = j / HID, h = j % HID;
    wsp[WS_W2P + j] = f2bf(W2[h * DIM + d]);
  } else if (i < 2 * HID * DIM + 32 * DIM) { // WdT[c][d] = w_down[c/8][d][c%8], rows>=24 zero
    int j = i - 2 * HID * DIM;
    int c = j / DIM, d = j % DIM;
    float v = (c < 24) ? wd[(c >> 3) * (DIM * 8) + d * 8 + (c & 7)] : 0.0f;
    wsp[WS_WDT + j] = f2bf(v);
  } else if (i < WS_ELEMS) {                 // WupT[d][c] = w_up_flat[c][d], cols>=24 zero
    int j = i - 2 * HID * DIM - 32 * DIM;
    int d = j >> 5, c = j & 31;
    float v = (c < 24) ? wu[c * DIM + d] : 0.0f;
    wsp[WS_WUPT + j] = f2bf(v);
  }
}

// ---------------- fused MLP + MoE-LoRA kernel ----------------
__global__ __launch_bounds__(NTHREADS, 2) void fused_k(
    const float* __restrict__ x,
    const float* __restrict__ topk_probs,
    const int*   __restrict__ topk_idx,
    const float* __restrict__ b1,
    const float* __restrict__ b2,
    const unsigned short* __restrict__ wsp,
    float* __restrict__ out)
{
  extern __shared__ char lds[];
  const int tid  = threadIdx.x;
  const int wid  = tid >> 6;
  const int lane = tid & 63;
  const int blockRow = blockIdx.x * BM;

  const int lrow = lane & 15;         // A row / B col / D col within 16x16 tile
  const int lkb  = (lane >> 4) * 8;   // k base within a 32-wide k-step

  // ---- stage X tile: f32 -> bf16 -> LDS (swizzled) ----
  {
    const float* xb = x + (size_t)blockRow * DIM;
    #pragma unroll
    for (int it = 0; it < (BM * DIM / 4) / NTHREADS; ++it) {   // 24 iters
      int idx = it * NTHREADS + tid;
      int row = idx / (DIM / 4);
      int c4  = idx % (DIM / 4);
      float4v v = *reinterpret_cast<const float4v*>(xb + row * DIM + c4 * 4);
      ushort4v u;
      u[0] = f2bf(v[0]); u[1] = f2bf(v[1]); u[2] = f2bf(v[2]); u[3] = f2bf(v[3]);
      int byte = row * 768 + c4 * 8;
      *reinterpret_cast<ushort4v*>(lds + L_XS + (byte ^ ((row & 7) << 4))) = u;
    }
  }
  // ---- stage WdT [32][384] into Ws (W1T-mode, 768B stride) ----
  {
    const unsigned short* src = wsp + WS_WDT;
    #pragma unroll
    for (int it = 0; it < (32 * DIM / 8) / NTHREADS; ++it) {   // 3 iters
      int idx = it * NTHREADS + tid;
      int f = idx / (DIM / 8), u8 = idx % (DIM / 8);
      ushort8v v = *reinterpret_cast<const ushort8v*>(src + f * DIM + u8 * 8);
      int byte = f * 768 + u8 * 16;
      *reinterpret_cast<ushort8v*>(lds + L_WS + (byte ^ ((f & 7) << 4))) = v;
    }
  }
  __syncthreads();

  // ---- MoE down: t1 = Xs @ WdT  -> [128][32] ----
  const int wrh = wid >> 1, wch = wid & 1;   // 4M x 2N wave grid
  float4v t1acc[2] = {};
  #pragma unroll
  for (int ks = 0; ks < 12; ++ks) {
    int kb = ks * 32 + lkb;
    int ra0 = wrh * 32 + lrow, ra1 = ra0 + 16;
    bf16x8 a0 = *reinterpret_cast<const bf16x8*>(lds + L_XS + ((ra0 * 768 + kb * 2) ^ ((ra0 & 7) << 4)));
    bf16x8 a1 = *reinterpret_cast<const bf16x8*>(lds + L_XS + ((ra1 * 768 + kb * 2) ^ ((ra1 & 7) << 4)));
    int rb = wch * 16 + lrow;
    bf16x8 b0 = *reinterpret_cast<const bf16x8*>(lds + L_WS + ((rb * 768 + kb * 2) ^ ((rb & 7) << 4)));
    t1acc[0] = __builtin_amdgcn_mfma_f32_16x16x32_bf16(a0, b0, t1acc[0], 0, 0, 0);
    t1acc[1] = __builtin_amdgcn_mfma_f32_16x16x32_bf16(a1, b0, t1acc[1], 0, 0, 0);
  }
  // G'[token][c] = prob(token, expert=c/8) * gelu(t1); cols 24..31 -> 0
  {
    int colg = wch * 16 + lrow;   // 0..31
    int e = colg >> 3;
    #pragma unroll
    for (int mt = 0; mt < 2; ++mt) {
      #pragma unroll
      for (int r = 0; r < 4; ++r) {
        int row = wrh * 32 + mt * 16 + (lane >> 4) * 4 + r;
        float g = 0.0f;
        if (e < 3) {
          int token = blockRow + row;
          float p = 0.0f;
          int i0 = topk_idx[token * 2 + 0];
          int i1 = topk_idx[token * 2 + 1];
          if (i0 == e) p += topk_probs[token * 2 + 0];
          if (i1 == e) p += topk_probs[token * 2 + 1];
          g = p * gelu_f(t1acc[mt][r]);
        }
        int byte = row * 128 + colg * 2;
        *reinterpret_cast<unsigned short*>(lds + L_HS + (byte ^ ((row & 7) << 4))) = f2bf(g);
      }
    }
  }
  __syncthreads();
  // ---- stage WupT [384][32] into Ws (W2T-mode, 128B stride, cols 0..31) ----
  {
    const unsigned short* src = wsp + WS_WUPT;
    #pragma unroll
    for (int it = 0; it < (DIM * 32 / 8) / NTHREADS; ++it) {   // 3 iters
      int idx = it * NTHREADS + tid;
      int d = idx / 4, u8 = idx & 3;
      ushort8v v = *reinterpret_cast<const ushort8v*>(src + d * 32 + u8 * 8);
      int byte = d * 128 + u8 * 16;
      *reinterpret_cast<ushort8v*>(lds + L_WS + (byte ^ ((d & 7) << 4))) = v;
    }
  }
  __syncthreads();

  // ---- output accumulators; fold in MoE up-projection (single K=32 step) ----
  const int wr = wid >> 2, wc = wid & 3;     // 2M x 4N wave grid for [128][384]
  float4v acc[4][6] = {};
  {
    bf16x8 A[4];
    #pragma unroll
    for (int mt = 0; mt < 4; ++mt) {
      int ra = wr * 64 + mt * 16 + lrow;
      A[mt] = *reinterpret_cast<const bf16x8*>(lds + L_HS + ((ra * 128 + lkb * 2) ^ ((ra & 7) << 4)));
    }
    #pragma unroll
    for (int nt = 0; nt < 6; ++nt) {
      int rb = wc * 96 + nt * 16 + lrow;
      bf16x8 b = *reinterpret_cast<const bf16x8*>(lds + L_WS + ((rb * 128 + lkb * 2) ^ ((rb & 7) << 4)));
      #pragma unroll
      for (int mt = 0; mt < 4; ++mt)
        acc[mt][nt] = __builtin_amdgcn_mfma_f32_16x16x32_bf16(A[mt], b, acc[mt][nt], 0, 0, 0);
    }
  }

  // ---- main loop over hidden chunks ----
  for (int c = 0; c < NCHUNK; ++c) {
    __syncthreads();   // previous readers of Ws/Hs are done
    // stage W1T chunk [64][384]
    {
      const unsigned short* src = wsp + WS_W1P + c * BH * DIM;
      #pragma unroll
      for (int it = 0; it < (BH * DIM / 8) / NTHREADS; ++it) {  // 6 iters
        int idx = it * NTHREADS + tid;
        int f = idx / (DIM / 8), u8 = idx % (DIM / 8);
        ushort8v v = *reinterpret_cast<const ushort8v*>(src + f * DIM + u8 * 8);
        int byte = f * 768 + u8 * 16;
        *reinterpret_cast<ushort8v*>(lds + L_WS + (byte ^ ((f & 7) << 4))) = v;
      }
    }
    __syncthreads();
    // G1: H = Xs @ W1Tc -> [128][64]
    float4v hacc[2][2] = {};
    #pragma unroll
    for (int ks = 0; ks < 12; ++ks) {
      int kb = ks * 32 + lkb;
      int ra0 = wrh * 32 + lrow, ra1 = ra0 + 16;
      bf16x8 a0 = *reinterpret_cast<const bf16x8*>(lds + L_XS + ((ra0 * 768 + kb * 2) ^ ((ra0 & 7) << 4)));
      bf16x8 a1 = *reinterpret_cast<const bf16x8*>(lds + L_XS + ((ra1 * 768 + kb * 2) ^ ((ra1 & 7) << 4)));
      int rb0 = wch * 32 + lrow, rb1 = rb0 + 16;
      bf16x8 b0 = *reinterpret_cast<const bf16x8*>(lds + L_WS + ((rb0 * 768 + kb * 2) ^ ((rb0 & 7) << 4)));
      bf16x8 b1v = *reinterpret_cast<const bf16x8*>(lds + L_WS + ((rb1 * 768 + kb * 2) ^ ((rb1 & 7) << 4)));
      hacc[0][0] = __builtin_amdgcn_mfma_f32_16x16x32_bf16(a0, b0,  hacc[0][0], 0, 0, 0);
      hacc[0][1] = __builtin_amdgcn_mfma_f32_16x16x32_bf16(a0, b1v, hacc[0][1], 0, 0, 0);
      hacc[1][0] = __builtin_amdgcn_mfma_f32_16x16x32_bf16(a1, b0,  hacc[1][0], 0, 0, 0);
      hacc[1][1] = __builtin_amdgcn_mfma_f32_16x16x32_bf16(a1, b1v, hacc[1][1], 0, 0, 0);
    }
    // bias + GELU -> Hs (bf16, swizzled)
    #pragma unroll
    for (int nt = 0; nt < 2; ++nt) {
      int colh = wch * 32 + nt * 16 + lrow;      // 0..63
      float bb = b1[c * BH + colh];
      #pragma unroll
      for (int mt = 0; mt < 2; ++mt) {
        #pragma unroll
        for (int r = 0; r < 4; ++r) {
          int row = wrh * 32 + mt * 16 + (lane >> 4) * 4 + r;
          float g = gelu_f(hacc[mt][nt][r] + bb);
          int byte = row * 128 + colh * 2;
          *reinterpret_cast<unsigned short*>(lds + L_HS + (byte ^ ((row & 7) << 4))) = f2bf(g);
        }
      }
    }
    __syncthreads();
    // stage W2T chunk [384][64]
    {
      const unsigned short* src = wsp + WS_W2P + c * BH;
      #pragma unroll
      for (int it = 0; it < (DIM * BH / 8) / NTHREADS; ++it) {  // 6 iters
        int idx = it * NTHREADS + tid;
        int d = idx / (BH / 8), u8 = idx % (BH / 8);
        ushort8v v = *reinterpret_cast<const ushort8v*>(src + d * HID + u8 * 8);
        int byte = d * 128 + u8 * 16;
        *reinterpret_cast<ushort8v*>(lds + L_WS + (byte ^ ((d & 7) << 4))) = v;
      }
    }
    __syncthreads();
    // G2: acc += Hs @ W2Tc  (K = 64 -> 2 k-steps)
    #pragma unroll
    for (int kk = 0; kk < 2; ++kk) {
      int kb = kk * 32 + lkb;
      bf16x8 A[4];
      #pragma unroll
      for (int mt = 0; mt < 4; ++mt) {
        int ra = wr * 64 + mt * 16 + lrow;
        A[mt] = *reinterpret_cast<const bf16x8*>(lds + L_HS + ((ra * 128 + kb * 2) ^ ((ra & 7) << 4)));
      }
      #pragma unroll
      for (int nt = 0; nt < 6; ++nt) {
        int rb = wc * 96 + nt * 16 + lrow;
        bf16x8 b = *reinterpret_cast<const bf16x8*>(lds + L_WS + ((rb * 128 + kb * 2) ^ ((rb & 7) << 4)));
        #pragma unroll
        for (int mt = 0; mt < 4; ++mt)
          acc[mt][nt] = __builtin_amdgcn_mfma_f32_16x16x32_bf16(A[mt], b, acc[mt][nt], 0, 0, 0);
      }
    }
  }

  // ---- epilogue: + b2, store f32 ----
  #pragma unroll
  for (int nt = 0; nt < 6; ++nt) {
    int col = wc * 96 + nt * 16 + lrow;
    float bb = b2[col];
    #pragma unroll
    for (int mt = 0; mt < 4; ++mt) {
      #pragma unroll
      for (int r = 0; r < 4; ++r) {
        int row = wr * 64 + mt * 16 + (lane >> 4) * 4 + r;
        out[(size_t)(blockRow + row) * DIM + col] = acc[mt][nt][r] + bb;
      }
    }
  }
}

extern "C" void kernel_launch(void* const* d_in, const int* in_sizes, int n_in,
                              void* d_out, int out_size, void* d_ws, size_t ws_size,
                              hipStream_t stream) {
  const float* x          = (const float*)d_in[0];
  // d_in[1] = gate (unused by reference)
  const float* topk_probs = (const float*)d_in[2];
  const int*   topk_idx   = (const int*)  d_in[3];
  const float* w_down     = (const float*)d_in[4];
  const float* w_up       = (const float*)d_in[5];
  const float* W1         = (const float*)d_in[6];
  const float* b1         = (const float*)d_in[7];
  const float* W2         = (const float*)d_in[8];
  const float* b2         = (const float*)d_in[9];
  float* out = (float*)d_out;

  if (ws_size < WS_BYTES_NEEDED) return;  // need ~2.4 MB scratch for packed weights

  hipFuncSetAttribute(reinterpret_cast<const void*>(fused_k),
                      hipFuncAttributeMaxDynamicSharedMemorySize, LDS_BYTES);

  unsigned short* wsp = (unsigned short*)d_ws;
  pack_weights_k<<<(WS_ELEMS + 255) / 256, 256, 0, stream>>>(W1, W2, w_down, w_up, wsp);
  fused_k<<<NBLOCKS, NTHREADS, LDS_BYTES, stream>>>(x, topk_probs, topk_idx, b1, b2, wsp, out);
}